// Round 1
// baseline (463.603 us; speedup 1.0000x reference)
//
#include <hip/hip_runtime.h>

// Problem constants (shapes fixed by setup_inputs)
constexpr int N_BLOCKS = 1024;
constexpr int BS       = 4;
constexpr int REM      = 3;
constexpr int ROW      = N_BLOCKS * BS + REM;   // 4099 floats per row
constexpr int GROUPS   = N_BLOCKS + 1;          // 1024 block-groups + 1 remainder group
constexpr unsigned ROWS  = 4u * 4096u;          // 16384
constexpr unsigned TOTAL = ROWS * GROUPS;       // 16,793,600 work items

__global__ __launch_bounds__(256) void blockcore_kernel(
    const float* __restrict__ x,
    const float* __restrict__ blocks,
    const float* __restrict__ diag,
    float* __restrict__ y)
{
    unsigned w = blockIdx.x * 256u + threadIdx.x;
    if (w >= TOTAL) return;

    unsigned row = w / GROUPS;          // constant divisor -> magic multiply
    unsigned g   = w - row * GROUPS;

    const float* xr = x + (size_t)row * ROW;
    float*       yr = y + (size_t)row * ROW;

    if (g < N_BLOCKS) {
        const int base = g * BS;
        // scalar loads: row base only 4B-aligned in general
        const float x0 = xr[base + 0];
        const float x1 = xr[base + 1];
        const float x2 = xr[base + 2];
        const float x3 = xr[base + 3];

        // blocks[g] is 64B-strided from an aligned base -> float4 loads legal.
        // y_j = dot(blocks[g][j][:], x)   (einsum '...nk,njk->...nj')
        const float4* bp = reinterpret_cast<const float4*>(blocks + (size_t)g * 16);
        const float4 r0 = bp[0];
        const float4 r1 = bp[1];
        const float4 r2 = bp[2];
        const float4 r3 = bp[3];

        yr[base + 0] = r0.x * x0 + r0.y * x1 + r0.z * x2 + r0.w * x3;
        yr[base + 1] = r1.x * x0 + r1.y * x1 + r1.z * x2 + r1.w * x3;
        yr[base + 2] = r2.x * x0 + r2.y * x1 + r2.z * x2 + r2.w * x3;
        yr[base + 3] = r3.x * x0 + r3.y * x1 + r3.z * x2 + r3.w * x3;
    } else {
        // remainder diagonal: 3 elements at the end of the row
        const int base = N_BLOCKS * BS;
        yr[base + 0] = xr[base + 0] * diag[0];
        yr[base + 1] = xr[base + 1] * diag[1];
        yr[base + 2] = xr[base + 2] * diag[2];
    }
}

extern "C" void kernel_launch(void* const* d_in, const int* in_sizes, int n_in,
                              void* d_out, int out_size, void* d_ws, size_t ws_size,
                              hipStream_t stream) {
    const float* x      = (const float*)d_in[0];
    const float* blocks = (const float*)d_in[1];
    const float* diag   = (const float*)d_in[2];
    float*       y      = (float*)d_out;

    const unsigned nblk = (TOTAL + 255u) / 256u;   // 65,600 blocks
    blockcore_kernel<<<dim3(nblk), dim3(256), 0, stream>>>(x, blocks, diag, y);
}